// Round 3
// baseline (168.970 us; speedup 1.0000x reference)
//
#include <hip/hip_runtime.h>
#include <hip/hip_bf16.h>
#include <stdint.h>

// out[4096,4096] = x[4096,2048] @ matrix[0,4096,2048]^T   (fp32 in/out)
// R6: cast pass unchanged. GEMM keeps R5's skeleton (256x256 tile, 8 waves,
// BK=64, 128 KiB dbuf LDS, 2 barriers/K-tile, counted vmcnt) but pipelines
// reads against MFMA *within* the tile in quadrant order (R4's order, zero
// extra barriers): {bF01+aF0-3 -> Q0}, {bF23 -> Q1}, {aF4-7 -> Q2}, sync,
// STAGE, {Q3 register-only}. A sched_group_barrier chain locks the
// DS_READ/MFMA interleave so the first MFMA waits on read #12, not #24,
// and the DS pipe stays busy under the MFMA bursts (LDS ~2.9Kcyc/tile vs
// MFMA ~2.5Kcyc/tile -- both pipes must overlap to pass 50% MfmaUtil).
// R3's verified XOR chunk swizzle (0 conflicts) + m89 C/D layout retained.

#define GAS __attribute__((address_space(1)))
#define LAS __attribute__((address_space(3)))

typedef __bf16 bf16x8 __attribute__((ext_vector_type(8)));
typedef float f32x4 __attribute__((ext_vector_type(4)));

static __device__ __forceinline__ unsigned short f2bf(float f) {
  union { float f; uint32_t u; } a; a.f = f;
  uint32_t u = a.u;
  u += 0x7FFFu + ((u >> 16) & 1u);   // round-to-nearest-even
  return (unsigned short)(u >> 16);
}

__global__ void cvt_f32_to_bf16(const float4* __restrict__ x,
                                const float4* __restrict__ m,
                                ushort4* __restrict__ xo,
                                ushort4* __restrict__ mo) {
  const int i = blockIdx.x * blockDim.x + threadIdx.x;
  const float4* __restrict__ src = blockIdx.y ? m : x;
  ushort4* __restrict__ dst      = blockIdx.y ? mo : xo;
  float4 v = src[i];
  ushort4 o;
  o.x = f2bf(v.x); o.y = f2bf(v.y); o.z = f2bf(v.z); o.w = f2bf(v.w);
  dst[i] = o;
}

#define MFMA16(a, b, c) __builtin_amdgcn_mfma_f32_16x16x32_bf16((a), (b), (c), 0, 0, 0)
#define SGB(mask, n) __builtin_amdgcn_sched_group_barrier((mask), (n), 0)

// C[M,N] = A[M,K]*B[N,K]^T, M=N=4096, K=2048. 512 threads = 8 waves.
// Block tile 256x256; wave (wm=wave>>2, wn=wave&3) owns rows wm*128..+128,
// cols wn*64..+64 as acc[8][4] of 16x16 frags. BK=64, NT=32 K-tiles.
// LDS: lds[buf][A/B][256*64]; global chunk c (8 elems=16B) of row r stored
// at physical chunk c^(r&7).
// Per K-tile t (buf p=t&1), quadrant-pipelined, 2 barriers:
//   reads bF01(4)+aF0-3(8) | MFMA Q0(16) | reads bF23(4) | MFMA Q1(16) |
//   reads aF4-7(8) | MFMA Q2(16)            [SGB chain locks interleave]
//   lgkmcnt(0)+barrier -> buf p free; STAGE(t+2 -> p)
//   MFMA Q3(16, register-only, hides stage issue)
//   vmcnt(8)+barrier   -> tile t+1 resident (t+2's 8 stay in flight)
__global__ __launch_bounds__(512, 2)
void gemm_bt_bf16(const unsigned short* __restrict__ A,
                  const unsigned short* __restrict__ B,
                  float* __restrict__ C) {
  constexpr int K  = 2048;
  constexpr int N  = 4096;
  constexpr int NT = K / 64;   // 32 K-tiles

  __shared__ __align__(16) unsigned short lds[2][2][256 * 64];   // 128 KiB

  const int tid  = threadIdx.x;
  const int wave = tid >> 6;
  const int lane = tid & 63;
  const int wm   = wave >> 2;   // 0..1
  const int wn   = wave & 3;    // 0..3

  // XCD-chunked swizzle (bijective over 256 blocks): XCD x gets tile-rows
  // [2x, 2x+2) -> 32 consecutive swizzled ids per XCD share 2 A-panels.
  const int bid = blockIdx.x;
  const int tm  = (bid & 7) * 2 + ((bid >> 3) >> 4);
  const int tn  = (bid >> 3) & 15;
  const int bM  = tm * 256;
  const int bN  = tn * 256;

  const int quad = lane >> 4;   // 0..3
  const int l15  = lane & 15;
  const int mx   = l15 & 7;     // = row&7 for all fragment rows

  // Staging: wave w covers rows [w*32, w*32+32) of A and of B, 4 insts each
  // (8 rows/inst). lane -> row lr=lane>>3, pre-swizzled source chunk lc.
  const int lr = lane >> 3;
  const int lc = (lane & 7) ^ lr;
  const size_t aBase = (size_t)(bM + wave * 32 + lr) * K + lc * 8;
  const size_t bBase = (size_t)(bN + wave * 32 + lr) * K + lc * 8;
  const int ldsW = wave * 32 * 64;   // elems

  // Per-lane fragment offsets (elems). Physical chunk = (ks*4+quad)^mx.
  const int aOff = (wm * 128 + l15) * 64;
  const int bOff = (wn * 64  + l15) * 64;
  const int ko0  = ((0 * 4 + quad) ^ mx) << 3;
  const int ko1  = ((1 * 4 + quad) ^ mx) << 3;

  f32x4 acc[8][4] = {};

#define STAGE(tau, pp) do {                                                              \
    const size_t kk_ = (size_t)(tau) * 64;                                               \
    _Pragma("unroll")                                                                    \
    for (int u = 0; u < 4; ++u)                                                          \
      __builtin_amdgcn_global_load_lds((const GAS void*)(A + aBase + kk_ + (size_t)u * 8 * K), \
                                       (LAS void*)(&lds[pp][0][ldsW + u * 512]), 16, 0, 0);    \
    _Pragma("unroll")                                                                    \
    for (int u = 0; u < 4; ++u)                                                          \
      __builtin_amdgcn_global_load_lds((const GAS void*)(B + bBase + kk_ + (size_t)u * 8 * K), \
                                       (LAS void*)(&lds[pp][1][ldsW + u * 512]), 16, 0, 0);    \
  } while (0)

  // Prologue: stage tiles 0 and 1; wait tile 0 only (tile 1 stays in flight).
  STAGE(0, 0);
  STAGE(1, 1);
  asm volatile("s_waitcnt vmcnt(8)" ::: "memory");
  __builtin_amdgcn_sched_barrier(0);
  __builtin_amdgcn_s_barrier();
  __builtin_amdgcn_sched_barrier(0);

  for (int t = 0; t < NT; ++t) {
    const int p = t & 1;
    const unsigned short* As = lds[p][0];
    const unsigned short* Bs = lds[p][1];

    bf16x8 aF[8][2], bF[4][2];

    // ---- group 1 reads: bF01 (4) + aF0-3 (8) ----
#pragma unroll
    for (int j = 0; j < 2; ++j) {
      bF[j][0] = *(const bf16x8*)(Bs + bOff + j * 1024 + ko0);
      bF[j][1] = *(const bf16x8*)(Bs + bOff + j * 1024 + ko1);
    }
#pragma unroll
    for (int i = 0; i < 4; ++i) {
      aF[i][0] = *(const bf16x8*)(As + aOff + i * 1024 + ko0);
      aF[i][1] = *(const bf16x8*)(As + aOff + i * 1024 + ko1);
    }
    // ---- MFMA Q0: rows 0-3 x cols 0-1 (16) ----
#pragma unroll
    for (int i = 0; i < 4; ++i)
#pragma unroll
      for (int j = 0; j < 2; ++j) {
        acc[i][j] = MFMA16(aF[i][0], bF[j][0], acc[i][j]);
        acc[i][j] = MFMA16(aF[i][1], bF[j][1], acc[i][j]);
      }

    // ---- group 2 reads: bF23 (4) ----
#pragma unroll
    for (int j = 2; j < 4; ++j) {
      bF[j][0] = *(const bf16x8*)(Bs + bOff + j * 1024 + ko0);
      bF[j][1] = *(const bf16x8*)(Bs + bOff + j * 1024 + ko1);
    }
    // ---- MFMA Q1: rows 0-3 x cols 2-3 (16) ----
#pragma unroll
    for (int i = 0; i < 4; ++i)
#pragma unroll
      for (int j = 2; j < 4; ++j) {
        acc[i][j] = MFMA16(aF[i][0], bF[j][0], acc[i][j]);
        acc[i][j] = MFMA16(aF[i][1], bF[j][1], acc[i][j]);
      }

    // ---- group 3 reads: aF4-7 (8) ----
#pragma unroll
    for (int i = 4; i < 8; ++i) {
      aF[i][0] = *(const bf16x8*)(As + aOff + i * 1024 + ko0);
      aF[i][1] = *(const bf16x8*)(As + aOff + i * 1024 + ko1);
    }
    // ---- MFMA Q2: rows 4-7 x cols 2-3 (16) ----
#pragma unroll
    for (int i = 4; i < 8; ++i)
#pragma unroll
      for (int j = 2; j < 4; ++j) {
        acc[i][j] = MFMA16(aF[i][0], bF[j][0], acc[i][j]);
        acc[i][j] = MFMA16(aF[i][1], bF[j][1], acc[i][j]);
      }

    // Lock the DS_READ/MFMA interleave (DS_READ=0x100, MFMA=0x8).
    SGB(0x100, 12); SGB(0x8, 16);
    SGB(0x100, 4);  SGB(0x8, 16);
    SGB(0x100, 8);  SGB(0x8, 16);

    // ---- free buf p, then stage tile t+2 into it ----
    if (t + 2 < NT) {
      asm volatile("s_waitcnt lgkmcnt(0)" ::: "memory");   // my 24 reads done
      __builtin_amdgcn_sched_barrier(0);
      __builtin_amdgcn_s_barrier();                        // everyone's done
      __builtin_amdgcn_sched_barrier(0);
      STAGE(t + 2, p);
    }

    // ---- MFMA Q3: rows 4-7 x cols 0-1 (16, register-only) ----
    __builtin_amdgcn_s_setprio(1);
#pragma unroll
    for (int i = 4; i < 8; ++i)
#pragma unroll
      for (int j = 0; j < 2; ++j) {
        acc[i][j] = MFMA16(aF[i][0], bF[j][0], acc[i][j]);
        acc[i][j] = MFMA16(aF[i][1], bF[j][1], acc[i][j]);
      }
    __builtin_amdgcn_s_setprio(0);

    // ---- admit tile t+1 (counted wait; never 0 until the tail) ----
    if (t + 1 < NT) {
      if (t + 2 < NT) asm volatile("s_waitcnt vmcnt(8)" ::: "memory");
      else            asm volatile("s_waitcnt vmcnt(0)" ::: "memory");
      __builtin_amdgcn_sched_barrier(0);
      __builtin_amdgcn_s_barrier();
      __builtin_amdgcn_sched_barrier(0);
    }
  }
#undef STAGE

  // Epilogue: C/D layout col=lane&15, row=quad*4+reg (m89-verified).
#pragma unroll
  for (int i = 0; i < 8; ++i) {
    const int row0 = bM + wm * 128 + i * 16 + quad * 4;
#pragma unroll
    for (int j = 0; j < 4; ++j) {
      const int col = bN + wn * 64 + j * 16 + l15;
#pragma unroll
      for (int tt = 0; tt < 4; ++tt)
        C[(size_t)(row0 + tt) * N + col] = acc[i][j][tt];
    }
  }
}

extern "C" void kernel_launch(void* const* d_in, const int* in_sizes, int n_in,
                              void* d_out, int out_size, void* d_ws, size_t ws_size,
                              hipStream_t stream) {
  const float* x   = (const float*)d_in[0];   // [4096, 2048]
  const float* mat = (const float*)d_in[1];   // [1, 4096, 2048]
  float* out = (float*)d_out;                 // [4096, 4096]

  constexpr size_t ELEMS = 4096ull * 2048ull;
  unsigned short* xb = (unsigned short*)d_ws;
  unsigned short* mb = xb + ELEMS;

  dim3 cgrid((unsigned)(ELEMS / 4 / 256), 2);
  cvt_f32_to_bf16<<<cgrid, 256, 0, stream>>>((const float4*)x, (const float4*)mat,
                                             (ushort4*)xb, (ushort4*)mb);

  // 256 blocks = 16x16 tiles of 256x256, 1 block/CU, XCD-swizzled in-kernel.
  gemm_bt_bf16<<<dim3(256), 512, 0, stream>>>(xb, mb, out);
}

// Round 4
// 165.232 us; speedup vs baseline: 1.0226x; 1.0226x over previous
//
#include <hip/hip_runtime.h>
#include <hip/hip_bf16.h>
#include <stdint.h>

// out[4096,4096] = x[4096,2048] @ matrix[0,4096,2048]^T   (fp32 in/out)
// R7: faithful m201 8-phase port. 256x256 tile, 8 waves, BK=64, 128 KiB dbuf
// LDS (buf0=even tiles, buf1=odd). Per 2 K-tiles: 8 phases, each {ds_reads,
// 2 x global_load_lds (one 64-row quarter), barrier, lgkmcnt(0), setprio(1),
// 16 MFMA, setprio(0), barrier}. Staging spread 2 loads/phase (m196: the
// fine ds_read||G-load||MFMA interleave is the lever; R4's bunched stage
// regressed). vmcnt(6) only at ph4/ph8 (6 loads stay in flight; drains
// exactly the tile read next); vmcnt(0) only in the last iteration.
// Stage windows verified: quarter staged >=1 phase after its reads retire.
// R3's XOR chunk swizzle (0 conflicts) + m89 C/D layout retained.

#define GAS __attribute__((address_space(1)))
#define LAS __attribute__((address_space(3)))

typedef __bf16 bf16x8 __attribute__((ext_vector_type(8)));
typedef float f32x4 __attribute__((ext_vector_type(4)));

static __device__ __forceinline__ unsigned short f2bf(float f) {
  union { float f; uint32_t u; } a; a.f = f;
  uint32_t u = a.u;
  u += 0x7FFFu + ((u >> 16) & 1u);   // round-to-nearest-even
  return (unsigned short)(u >> 16);
}

__global__ void cvt_f32_to_bf16(const float4* __restrict__ x,
                                const float4* __restrict__ m,
                                ushort4* __restrict__ xo,
                                ushort4* __restrict__ mo) {
  const int i = blockIdx.x * blockDim.x + threadIdx.x;
  const float4* __restrict__ src = blockIdx.y ? m : x;
  ushort4* __restrict__ dst      = blockIdx.y ? mo : xo;
  float4 v = src[i];
  ushort4 o;
  o.x = f2bf(v.x); o.y = f2bf(v.y); o.z = f2bf(v.z); o.w = f2bf(v.w);
  dst[i] = o;
}

#define MFMA16(a, b, c) __builtin_amdgcn_mfma_f32_16x16x32_bf16((a), (b), (c), 0, 0, 0)

// C[M,N] = A[M,K]*B[N,K]^T, M=N=4096, K=2048. 512 threads = 8 waves.
// Wave (wm=wave>>2, wn=wave&3) owns rows wm*128..+128, cols wn*64..+64 as
// acc[8][4] of 16x16 frags. NT=32 K-tiles, NITER=16 (2 tiles/iter).
// LDS lds[buf][A/B][256*64]; global chunk c (16B) of row r at phys c^(r&7).
// Phase schedule per iteration (tile t0=2*it in buf0 ph1-4, t0+1 in buf1
// ph5-8); stage unit = 64 rows (A-q or B-q), 1 inst/thread, 2 units/phase:
//  ph1: rd bF01+aF0-3(12); stg t0+1:Aq1,Aq3->b1 ; MFMA Q0(i0-3,j0-1)
//  ph2: rd bF23(4)       ; stg t0+2:Aq0,Aq2->b0 ; MFMA Q1(i0-3,j2-3)
//  ph3: rd aF4-7(8)      ; stg t0+2:Bq0,Bq1->b0 ; MFMA Q2(i4-7,j2-3)
//  ph4: --               ; stg t0+2:Bq2,Bq3->b0 ; vmcnt(6); MFMA Q3(i4-7,j0-1)
//  ph5-8: same on buf1; stages: t0+2:Aq1,Aq3->b0 / t0+3:Aq0,Aq2->b1 /
//         t0+3:Bq0,Bq1->b1 / t0+3:Bq2,Bq3->b1 + vmcnt(6)
// vmcnt(6)@ph4 drains tile t0+1 (read ph5); @ph8 drains t0+2 (read next ph1).
__global__ __launch_bounds__(512, 2)
void gemm_bt_bf16(const unsigned short* __restrict__ A,
                  const unsigned short* __restrict__ B,
                  float* __restrict__ C) {
  constexpr int K     = 2048;
  constexpr int N     = 4096;
  constexpr int NT    = K / 64;    // 32
  constexpr int NITER = NT / 2;    // 16

  __shared__ __align__(16) unsigned short lds[2][2][256 * 64];   // 128 KiB

  const int tid  = threadIdx.x;
  const int wave = tid >> 6;
  const int lane = tid & 63;
  const int wm   = wave >> 2;   // 0..1
  const int wn   = wave & 3;    // 0..3

  // XCD-chunked swizzle (bijective over 256 blocks).
  const int bid = blockIdx.x;
  const int tm  = (bid & 7) * 2 + ((bid >> 3) >> 4);
  const int tn  = (bid >> 3) & 15;
  const int bM  = tm * 256;
  const int bN  = tn * 256;

  const int quad = lane >> 4;   // 0..3
  const int l15  = lane & 15;
  const int mx   = l15 & 7;

  // Staging: unit = 64 rows; wave w covers rows unit_base + w*8 + lr2.
  const int lr2 = lane >> 3;              // 0..7
  const int lcc = (lane & 7) ^ lr2;       // pre-swizzled source chunk
  const size_t aSB = (size_t)(bM + wave * 8 + lr2) * K + lcc * 8;
  const size_t bSB = (size_t)(bN + wave * 8 + lr2) * K + lcc * 8;

  // Fragment read offsets (elems). Physical chunk = (ks*4+quad)^mx.
  const int aOff = (wm * 128 + l15) * 64;
  const int bOff = (wn * 64  + l15) * 64;
  const int ko0  = ((0 * 4 + quad) ^ mx) << 3;
  const int ko1  = ((1 * 4 + quad) ^ mx) << 3;

  f32x4 acc[8][4] = {};
  bf16x8 aF[4][2], bF[4][2];

#define STG_A(q, tau, bb) do { if ((tau) < NT)                                             \
    __builtin_amdgcn_global_load_lds(                                                      \
      (const GAS void*)(A + aSB + (size_t)(q) * 64 * K + (size_t)(tau) * 64),              \
      (LAS void*)(&lds[bb][0][((q) * 64 + wave * 8) * 64]), 16, 0, 0); } while (0)
#define STG_B(q, tau, bb) do { if ((tau) < NT)                                             \
    __builtin_amdgcn_global_load_lds(                                                      \
      (const GAS void*)(B + bSB + (size_t)(q) * 64 * K + (size_t)(tau) * 64),              \
      (LAS void*)(&lds[bb][1][((q) * 64 + wave * 8) * 64]), 16, 0, 0); } while (0)

  // Prologue: tile0 (8 units) + tile1 (6 units: Aq0,Aq2,B*); vmcnt(6)
  // drains tile0, leaves tile1's 6 in flight (ph1 adds its last 2).
  STG_A(0, 0, 0); STG_A(1, 0, 0); STG_A(2, 0, 0); STG_A(3, 0, 0);
  STG_B(0, 0, 0); STG_B(1, 0, 0); STG_B(2, 0, 0); STG_B(3, 0, 0);
  STG_A(0, 1, 1); STG_A(2, 1, 1);
  STG_B(0, 1, 1); STG_B(1, 1, 1); STG_B(2, 1, 1); STG_B(3, 1, 1);
  asm volatile("s_waitcnt vmcnt(6)" ::: "memory");
  __builtin_amdgcn_sched_barrier(0);
  __builtin_amdgcn_s_barrier();
  __builtin_amdgcn_sched_barrier(0);

#pragma unroll 1
  for (int it = 0; it < NITER; ++it) {
    const int t0 = 2 * it;
    const bool lastIt = (it == NITER - 1);
    const unsigned short* A0 = lds[0][0];
    const unsigned short* B0 = lds[0][1];
    const unsigned short* A1 = lds[1][0];
    const unsigned short* B1 = lds[1][1];

    // ================= tile t0, buf0: phases 1-4 =================
    // ---- ph1 ----
#pragma unroll
    for (int j = 0; j < 2; ++j) {
      bF[j][0] = *(const bf16x8*)(B0 + bOff + j * 1024 + ko0);
      bF[j][1] = *(const bf16x8*)(B0 + bOff + j * 1024 + ko1);
    }
#pragma unroll
    for (int i = 0; i < 4; ++i) {
      aF[i][0] = *(const bf16x8*)(A0 + aOff + i * 1024 + ko0);
      aF[i][1] = *(const bf16x8*)(A0 + aOff + i * 1024 + ko1);
    }
    STG_A(1, t0 + 1, 1); STG_A(3, t0 + 1, 1);
    asm volatile("s_waitcnt lgkmcnt(8)" ::: "memory");
    __builtin_amdgcn_s_barrier();
    asm volatile("s_waitcnt lgkmcnt(0)" ::: "memory");
    __builtin_amdgcn_sched_barrier(0);
    __builtin_amdgcn_s_setprio(1);
#pragma unroll
    for (int i = 0; i < 4; ++i)
#pragma unroll
      for (int j = 0; j < 2; ++j) {
        acc[i][j] = MFMA16(aF[i][0], bF[j][0], acc[i][j]);
        acc[i][j] = MFMA16(aF[i][1], bF[j][1], acc[i][j]);
      }
    __builtin_amdgcn_s_setprio(0);
    __builtin_amdgcn_s_barrier();

    // ---- ph2 ----
#pragma unroll
    for (int j = 2; j < 4; ++j) {
      bF[j][0] = *(const bf16x8*)(B0 + bOff + j * 1024 + ko0);
      bF[j][1] = *(const bf16x8*)(B0 + bOff + j * 1024 + ko1);
    }
    STG_A(0, t0 + 2, 0); STG_A(2, t0 + 2, 0);
    __builtin_amdgcn_s_barrier();
    asm volatile("s_waitcnt lgkmcnt(0)" ::: "memory");
    __builtin_amdgcn_sched_barrier(0);
    __builtin_amdgcn_s_setprio(1);
#pragma unroll
    for (int i = 0; i < 4; ++i)
#pragma unroll
      for (int j = 2; j < 4; ++j) {
        acc[i][j] = MFMA16(aF[i][0], bF[j][0], acc[i][j]);
        acc[i][j] = MFMA16(aF[i][1], bF[j][1], acc[i][j]);
      }
    __builtin_amdgcn_s_setprio(0);
    __builtin_amdgcn_s_barrier();

    // ---- ph3 ----
#pragma unroll
    for (int i = 0; i < 4; ++i) {
      aF[i][0] = *(const bf16x8*)(A0 + aOff + (4 + i) * 1024 + ko0);
      aF[i][1] = *(const bf16x8*)(A0 + aOff + (4 + i) * 1024 + ko1);
    }
    STG_B(0, t0 + 2, 0); STG_B(1, t0 + 2, 0);
    __builtin_amdgcn_s_barrier();
    asm volatile("s_waitcnt lgkmcnt(0)" ::: "memory");
    __builtin_amdgcn_sched_barrier(0);
    __builtin_amdgcn_s_setprio(1);
#pragma unroll
    for (int i = 0; i < 4; ++i)
#pragma unroll
      for (int j = 2; j < 4; ++j) {
        acc[4 + i][j] = MFMA16(aF[i][0], bF[j][0], acc[4 + i][j]);
        acc[4 + i][j] = MFMA16(aF[i][1], bF[j][1], acc[4 + i][j]);
      }
    __builtin_amdgcn_s_setprio(0);
    __builtin_amdgcn_s_barrier();

    // ---- ph4 ----
    STG_B(2, t0 + 2, 0); STG_B(3, t0 + 2, 0);
    if (!lastIt) asm volatile("s_waitcnt vmcnt(6)" ::: "memory");
    else         asm volatile("s_waitcnt vmcnt(0)" ::: "memory");
    __builtin_amdgcn_sched_barrier(0);
    __builtin_amdgcn_s_barrier();
    __builtin_amdgcn_s_setprio(1);
#pragma unroll
    for (int i = 0; i < 4; ++i)
#pragma unroll
      for (int j = 0; j < 2; ++j) {
        acc[4 + i][j] = MFMA16(aF[i][0], bF[j][0], acc[4 + i][j]);
        acc[4 + i][j] = MFMA16(aF[i][1], bF[j][1], acc[4 + i][j]);
      }
    __builtin_amdgcn_s_setprio(0);
    __builtin_amdgcn_s_barrier();

    // ================= tile t0+1, buf1: phases 5-8 =================
    // ---- ph5 ----
#pragma unroll
    for (int j = 0; j < 2; ++j) {
      bF[j][0] = *(const bf16x8*)(B1 + bOff + j * 1024 + ko0);
      bF[j][1] = *(const bf16x8*)(B1 + bOff + j * 1024 + ko1);
    }
#pragma unroll
    for (int i = 0; i < 4; ++i) {
      aF[i][0] = *(const bf16x8*)(A1 + aOff + i * 1024 + ko0);
      aF[i][1] = *(const bf16x8*)(A1 + aOff + i * 1024 + ko1);
    }
    STG_A(1, t0 + 2, 0); STG_A(3, t0 + 2, 0);
    asm volatile("s_waitcnt lgkmcnt(8)" ::: "memory");
    __builtin_amdgcn_s_barrier();
    asm volatile("s_waitcnt lgkmcnt(0)" ::: "memory");
    __builtin_amdgcn_sched_barrier(0);
    __builtin_amdgcn_s_setprio(1);
#pragma unroll
    for (int i = 0; i < 4; ++i)
#pragma unroll
      for (int j = 0; j < 2; ++j) {
        acc[i][j] = MFMA16(aF[i][0], bF[j][0], acc[i][j]);
        acc[i][j] = MFMA16(aF[i][1], bF[j][1], acc[i][j]);
      }
    __builtin_amdgcn_s_setprio(0);
    __builtin_amdgcn_s_barrier();

    // ---- ph6 ----
#pragma unroll
    for (int j = 2; j < 4; ++j) {
      bF[j][0] = *(const bf16x8*)(B1 + bOff + j * 1024 + ko0);
      bF[j][1] = *(const bf16x8*)(B1 + bOff + j * 1024 + ko1);
    }
    STG_A(0, t0 + 3, 1); STG_A(2, t0 + 3, 1);
    __builtin_amdgcn_s_barrier();
    asm volatile("s_waitcnt lgkmcnt(0)" ::: "memory");
    __builtin_amdgcn_sched_barrier(0);
    __builtin_amdgcn_s_setprio(1);
#pragma unroll
    for (int i = 0; i < 4; ++i)
#pragma unroll
      for (int j = 2; j < 4; ++j) {
        acc[i][j] = MFMA16(aF[i][0], bF[j][0], acc[i][j]);
        acc[i][j] = MFMA16(aF[i][1], bF[j][1], acc[i][j]);
      }
    __builtin_amdgcn_s_setprio(0);
    __builtin_amdgcn_s_barrier();

    // ---- ph7 ----
#pragma unroll
    for (int i = 0; i < 4; ++i) {
      aF[i][0] = *(const bf16x8*)(A1 + aOff + (4 + i) * 1024 + ko0);
      aF[i][1] = *(const bf16x8*)(A1 + aOff + (4 + i) * 1024 + ko1);
    }
    STG_B(0, t0 + 3, 1); STG_B(1, t0 + 3, 1);
    __builtin_amdgcn_s_barrier();
    asm volatile("s_waitcnt lgkmcnt(0)" ::: "memory");
    __builtin_amdgcn_sched_barrier(0);
    __builtin_amdgcn_s_setprio(1);
#pragma unroll
    for (int i = 0; i < 4; ++i)
#pragma unroll
      for (int j = 2; j < 4; ++j) {
        acc[4 + i][j] = MFMA16(aF[i][0], bF[j][0], acc[4 + i][j]);
        acc[4 + i][j] = MFMA16(aF[i][1], bF[j][1], acc[4 + i][j]);
      }
    __builtin_amdgcn_s_setprio(0);
    __builtin_amdgcn_s_barrier();

    // ---- ph8 ----
    STG_B(2, t0 + 3, 1); STG_B(3, t0 + 3, 1);
    if (!lastIt) asm volatile("s_waitcnt vmcnt(6)" ::: "memory");
    else         asm volatile("s_waitcnt vmcnt(0)" ::: "memory");
    __builtin_amdgcn_sched_barrier(0);
    __builtin_amdgcn_s_barrier();
    __builtin_amdgcn_s_setprio(1);
#pragma unroll
    for (int i = 0; i < 4; ++i)
#pragma unroll
      for (int j = 0; j < 2; ++j) {
        acc[4 + i][j] = MFMA16(aF[i][0], bF[j][0], acc[4 + i][j]);
        acc[4 + i][j] = MFMA16(aF[i][1], bF[j][1], acc[4 + i][j]);
      }
    __builtin_amdgcn_s_setprio(0);
    __builtin_amdgcn_s_barrier();
  }
#undef STG_A
#undef STG_B

  // Epilogue: C/D layout col=lane&15, row=quad*4+reg (m89-verified).
#pragma unroll
  for (int i = 0; i < 8; ++i) {
    const int row0 = bM + wm * 128 + i * 16 + quad * 4;
#pragma unroll
    for (int j = 0; j < 4; ++j) {
      const int col = bN + wn * 64 + j * 16 + l15;
#pragma unroll
      for (int tt = 0; tt < 4; ++tt)
        C[(size_t)(row0 + tt) * N + col] = acc[i][j][tt];
    }
  }
}

extern "C" void kernel_launch(void* const* d_in, const int* in_sizes, int n_in,
                              void* d_out, int out_size, void* d_ws, size_t ws_size,
                              hipStream_t stream) {
  const float* x   = (const float*)d_in[0];   // [4096, 2048]
  const float* mat = (const float*)d_in[1];   // [1, 4096, 2048]
  float* out = (float*)d_out;                 // [4096, 4096]

  constexpr size_t ELEMS = 4096ull * 2048ull;
  unsigned short* xb = (unsigned short*)d_ws;
  unsigned short* mb = xb + ELEMS;

  dim3 cgrid((unsigned)(ELEMS / 4 / 256), 2);
  cvt_f32_to_bf16<<<cgrid, 256, 0, stream>>>((const float4*)x, (const float4*)mat,
                                             (ushort4*)xb, (ushort4*)mb);

  // 256 blocks = 16x16 tiles of 256x256, 1 block/CU, XCD-swizzled in-kernel.
  gemm_bt_bf16<<<dim3(256), 512, 0, stream>>>(xb, mb, out);
}